// Round 6
// baseline (146.189 us; speedup 1.0000x reference)
//
#include <hip/hip_runtime.h>
#include <stdint.h>

#define BB 64
#define TT 512
#define HH 1024
#define CC 21

#define GAS __attribute__((address_space(1)))
#define LAS __attribute__((address_space(3)))
// async global->LDS, 16B per lane, dest = wave-uniform base + lane*16
__device__ __forceinline__ void gll16(const void* g, void* l) {
    __builtin_amdgcn_global_load_lds((const GAS uint32_t*)g, (LAS uint32_t*)l, 16, 0, 0);
}

#define RL(x, lane) __uint_as_float(__builtin_amdgcn_readlane(__float_as_uint(x), (lane)))

// ---------------------------------------------------------------------------
// K1: logits = seq @ W + b.  512 blocks x 512 threads (8 waves).
// Wave w owns h-eighth [w*128,+128) of the block's 64 rows (lane = row).
// W: wave-uniform scalar reads -> s_load into SGPRs (scalar pipe, NOT the
//    LDS pipe — round-5's wall was 154K cy/CU of uniform ds_read_b128).
//    84 floats per 4-h sub-chunk fits the SGPR budget; 4 waves/SIMD hide
//    the ~200cy L2 s_load latency.
// X: direct global->VGPR float4 per sub-chunk, depth-2 rotated prefetch
//    (per-lane row; lines fully consumed across sub-chunks; L2/L3 absorb).
// LDS: only the 8-way combine scratch (stride 25 -> conflict-free).
// ---------------------------------------------------------------------------
__global__ __launch_bounds__(512) void logits_kernel(
    const float* __restrict__ seq,   // [B*T, H]
    const float* __restrict__ W,     // [H, C]
    const float* __restrict__ bias,  // [C]
    float* __restrict__ logits)      // [B*T, C]
{
    __shared__ float comb[7][64][25];   // 44800 B

    const int t = threadIdx.x;
    const int w = __builtin_amdgcn_readfirstlane(t >> 6);  // force wave-uniform
    const int l = t & 63;
    const int row0 = blockIdx.x * 64;
    const float* xrow  = seq + (size_t)(row0 + l) * HH + w * 128;  // per-lane
    const float* wbase = W + (size_t)w * 128 * CC;                 // uniform

    float acc[CC];
#pragma unroll
    for (int c = 0; c < CC; ++c) acc[c] = 0.f;

    float4 xb0 = *(const float4*)(xrow);
    float4 xb1 = *(const float4*)(xrow + 4);

#pragma unroll 2
    for (int s = 0; s < 32; ++s) {
        float4 xv = (s & 1) ? xb1 : xb0;
        if (s + 2 < 32) {
            float4 nv = *(const float4*)(xrow + (s + 2) * 4);
            if (s & 1) xb1 = nv; else xb0 = nv;
        }
        const float* wp = wbase + s * 84;   // uniform -> s_load batches
#pragma unroll
        for (int j = 0; j < 4; ++j) {
            float xc = (&xv.x)[j];
#pragma unroll
            for (int c = 0; c < CC; ++c)
                acc[c] += xc * wp[j * CC + c];
        }
    }

    // 8-way combine: waves 1..7 write partials, wave 0 sums + bias + store
    if (w > 0) {
        float* cr = &comb[w - 1][l][0];
#pragma unroll
        for (int c = 0; c < CC; ++c) cr[c] = acc[c];
    }
    __syncthreads();
    if (w == 0) {
        float* orow = logits + (size_t)(row0 + l) * CC;
#pragma unroll
        for (int c = 0; c < CC; ++c) {
            float s = acc[c] + bias[c];
#pragma unroll
            for (int i = 0; i < 7; ++i) s += comb[i][l][c];
            orow[c] = s;
        }
    }
}

// ---------------------------------------------------------------------------
// K2: Viterbi. One block (256 threads) per batch. Wave 0: serial forward scan,
// now with the exec-mask hoisted around the whole loop (readlane ignores exec),
// pointer-increment addressing, and 2-deep lgt prefetch -> ~120cy/step issue.
// Backpointers recomputed in parallel afterwards (bit-exact). Backtrack via
// 12 chunked candidate pointer-maps (integer, exact). One-hot by 252 threads.
// ---------------------------------------------------------------------------
__global__ __launch_bounds__(256) void viterbi_kernel(
    const float* __restrict__ logits,  // [B, T, C]
    const int* __restrict__ mask,      // [B, T]
    const float* __restrict__ trans,   // [C, C]
    float* __restrict__ onehot)        // [B, T, C]
{
    __shared__ __align__(16) float lg[(TT + 2) * CC];   // +2 rows: prefetch pad
    __shared__ float stS[TT * CC];
    __shared__ float trL[CC * CC];
    __shared__ unsigned char bp[TT * CC];
    __shared__ unsigned char tagl[TT];
    __shared__ unsigned char mapl[12 * CC];
    __shared__ unsigned char bnd[13];

    const int tid = threadIdx.x;
    const int w = tid >> 6;
    const int l = tid & 63;
    const int b = blockIdx.x;

    // stage logits[b] -> LDS
    const float* lb = logits + (size_t)b * TT * CC;
    for (int i = w; i < 42; i += 4)
        gll16(lb + (size_t)(i * 64 + l) * 4, &lg[i * 256]);

    for (int j = tid; j < CC * CC; j += 256) trL[j] = trans[j];

    int sl = 0;
#pragma unroll
    for (int k = 0; k < 8; ++k) sl += mask[b * TT + k * 64 + l];
#pragma unroll
    for (int o = 32; o > 0; o >>= 1) sl += __shfl_xor(sl, o);
    const int idstart = (sl >= 1) ? (sl - 1) : 0;

    asm volatile("s_waitcnt vmcnt(0)" ::: "memory");
    __syncthreads();

    if (w == 0) {
        // ---- forward scan (lanes 0..20 only; single exec-mask flip) ----
        const bool act = (l < CC);
        if (act) {
            const int cc = l;
            float tcol[CC];
#pragma unroll
            for (int cp = 0; cp < CC; ++cp) tcol[cp] = trL[cp * CC + cc];

            float st = lg[cc];
            stS[l] = st;
            int lgo = CC + cc;
            float lg1 = lg[lgo];
            float lg2 = lg[lgo + CC];
            int sto = CC + l;

#pragma unroll 1
            for (int t = 1; t < sl; ++t) {
                float sc[CC];
#pragma unroll
                for (int cp = 0; cp < CC; ++cp) sc[cp] = RL(st, cp) + tcol[cp];
                float m0 = fmaxf(fmaxf(sc[0], sc[1]), sc[2]);
                float m1 = fmaxf(fmaxf(sc[3], sc[4]), sc[5]);
                float m2 = fmaxf(fmaxf(sc[6], sc[7]), sc[8]);
                float m3 = fmaxf(fmaxf(sc[9], sc[10]), sc[11]);
                float m4 = fmaxf(fmaxf(sc[12], sc[13]), sc[14]);
                float m5 = fmaxf(fmaxf(sc[15], sc[16]), sc[17]);
                float m6 = fmaxf(fmaxf(sc[18], sc[19]), sc[20]);
                float n0 = fmaxf(fmaxf(m0, m1), m2);
                float n1 = fmaxf(fmaxf(m3, m4), m5);
                float best = fmaxf(fmaxf(n0, n1), m6);
                st = best + lg1;
                lg1 = lg2;
                lg2 = lg[lgo + 2 * CC];     // row <= sl+1 <= 513: padded, safe
                lgo += CC;
                stS[sto] = st;
                sto += CC;
            }

            // last_tag = first-max over final state
            float fs[CC];
#pragma unroll
            for (int cp = 0; cp < CC; ++cp) fs[cp] = RL(st, cp);
            float q0 = fmaxf(fmaxf(fs[0], fs[1]), fs[2]);
            float q1 = fmaxf(fmaxf(fs[3], fs[4]), fs[5]);
            float q2 = fmaxf(fmaxf(fs[6], fs[7]), fs[8]);
            float q3 = fmaxf(fmaxf(fs[9], fs[10]), fs[11]);
            float q4 = fmaxf(fmaxf(fs[12], fs[13]), fs[14]);
            float q5 = fmaxf(fmaxf(fs[15], fs[16]), fs[17]);
            float q6 = fmaxf(fmaxf(fs[18], fs[19]), fs[20]);
            float fbest = fmaxf(fmaxf(fmaxf(q0, q1), fmaxf(q2, q3)),
                                fmaxf(fmaxf(q4, q5), q6));
            int e[CC];
#pragma unroll
            for (int cp = 0; cp < CC; ++cp) e[cp] = (fs[cp] == fbest) ? cp : 63;
            int i0 = min(min(e[0], e[1]), e[2]);
            int i1 = min(min(e[3], e[4]), e[5]);
            int i2 = min(min(e[6], e[7]), e[8]);
            int i3 = min(min(e[9], e[10]), e[11]);
            int i4 = min(min(e[12], e[13]), e[14]);
            int i5 = min(min(e[15], e[16]), e[17]);
            int i6 = min(min(e[18], e[19]), e[20]);
            int last = min(min(min(i0, i1), min(i2, i3)), min(min(i4, i5), i6));
            if (l == 0) tagl[TT - 1] = (unsigned char)last;
        }
    } else {
        // identity backpointers for p in [idstart, TT)
        int s = (w - 1) * 64 + l;                  // 0..191
        if (s < 189) {
            int c0 = s % CC, prow = s / CC;        // 9 rows/pass
#pragma unroll 1
            for (int p = idstart + prow; p < TT; p += 9)
                bp[p * CC + c0] = (unsigned char)c0;
        }
    }
    __syncthreads();

    // ---- parallel bp recompute for valid steps ----
    if (tid < 252) {
        const int c0 = tid % CC, tg = tid / CC;    // 12 rows/pass
        float tc[CC];
#pragma unroll
        for (int cp = 0; cp < CC; ++cp) tc[cp] = trL[cp * CC + c0];
#pragma unroll 1
        for (int t = 1 + tg; t < sl; t += 12) {
            const float* sp = stS + (t - 1) * CC;
            float bv = sp[0] + tc[0];
            int bi = 0;
#pragma unroll
            for (int cp = 1; cp < CC; ++cp) {
                float v = sp[cp] + tc[cp];
                bool g = v > bv;                   // strict >: first-max
                bv = g ? v : bv;
                bi = g ? cp : bi;
            }
            bp[(t - 1) * CC + c0] = (unsigned char)bi;
        }
    }
    __syncthreads();

    // ---- Phase A: candidate maps for 12 chunks of 43 steps ----
    if (tid < 252) {
        int g = tid / CC, cand = tid % CC;
        int endp = g * 43;
        int startp = min(g * 43 + 42, TT - 2);
        int m = cand;
#pragma unroll 1
        for (int i = 0; i < 43; ++i) {
            int p = startp - i;
            int pr = (p >= endp) ? p : endp;
            int m2 = bp[pr * CC + m];
            m = (p >= endp) ? m2 : m;
        }
        mapl[g * CC + cand] = (unsigned char)m;
    }
    __syncthreads();

    // ---- Phase B: compose boundary tags ----
    if (tid == 0) {
        int eb = tagl[TT - 1];
        bnd[12] = (unsigned char)eb;
        for (int g = 11; g >= 0; --g) {
            eb = mapl[g * CC + eb];
            bnd[g] = (unsigned char)eb;
        }
    }
    __syncthreads();

    // ---- Phase C: replay 12 chunks in parallel ----
    if (tid < 12) {
        int g = tid;
        int endp = g * 43;
        int startp = min(g * 43 + 42, TT - 2);
        int eb = bnd[g + 1];
#pragma unroll 1
        for (int p = startp; p >= endp; --p) {
            eb = bp[p * CC + eb];
            tagl[p] = (unsigned char)eb;
        }
    }
    __syncthreads();

    // ---- Phase D: one-hot write ----
    if (tid < 252) {
        const int c0 = tid % CC, prow = tid / CC;
        float* ob = onehot + (size_t)b * TT * CC;
#pragma unroll 1
        for (int p = prow; p < TT; p += 12)
            ob[(size_t)p * CC + c0] = (c0 == (int)tagl[p]) ? 1.f : 0.f;
    }
}

extern "C" void kernel_launch(void* const* d_in, const int* in_sizes, int n_in,
                              void* d_out, int out_size, void* d_ws, size_t ws_size,
                              hipStream_t stream) {
    const float* seq   = (const float*)d_in[0];  // [B,T,H] f32
    const int*   msk   = (const int*)d_in[1];    // [B,T] i32
    const float* W     = (const float*)d_in[2];  // [H,C] f32
    const float* bias  = (const float*)d_in[3];  // [C] f32
    const float* trans = (const float*)d_in[4];  // [C,C] f32

    float* onehot_out = (float*)d_out;                     // output 0: [B,T,C]
    float* logits_out = onehot_out + (size_t)BB * TT * CC; // output 1: [B,T,C]

    logits_kernel<<<512, 512, 0, stream>>>(seq, W, bias, logits_out);
    viterbi_kernel<<<BB, 256, 0, stream>>>(logits_out, msk, trans, onehot_out);
}

// Round 7
// 134.990 us; speedup vs baseline: 1.0830x; 1.0830x over previous
//
#include <hip/hip_runtime.h>
#include <stdint.h>

#define BB 64
#define TT 512
#define HH 1024
#define CC 21

#define GAS __attribute__((address_space(1)))
#define LAS __attribute__((address_space(3)))
// async global->LDS, 16B per lane, dest = wave-uniform base + lane*16
__device__ __forceinline__ void gll16(const void* g, void* l) {
    __builtin_amdgcn_global_load_lds((const GAS uint32_t*)g, (LAS uint32_t*)l, 16, 0, 0);
}

#define RL(x, lane) __uint_as_float(__builtin_amdgcn_readlane(__float_as_uint(x), (lane)))

// ---------------------------------------------------------------------------
// K1: logits = seq @ W + b.  256 blocks x 512 threads (8 waves).
// Block = 128 rows; wave w owns h-eighth [w*128,+128); lane owns rows l and
// l+64 (R=2). W slab (16h x 21 = 336 floats) lives in 6 VGPRs per lane
// (coalesced global load, L2-hot) and is broadcast via v_readlane with
// compile-time lane indices: 336 RL feed 672 FMAs -> 1.5 instr/FMA, no LDS
// pipe, no s_load latency (round-6's wall), no bank conflicts.
// X: direct global->VGPR float4, depth-1 chunk prefetch (bytes exactly
// consumed; L2 absorbs the per-lane row stride). LDS only for the 8-way
// combine (stride-22 rows -> 2-way bank aliasing = free).
// ---------------------------------------------------------------------------
__global__ __launch_bounds__(512) void logits_kernel(
    const float* __restrict__ seq,   // [B*T, H]
    const float* __restrict__ W,     // [H, C]
    const float* __restrict__ bias,  // [C]
    float* __restrict__ logits)      // [B*T, C]
{
    __shared__ float comb[7][128][22];   // 78848 B

    const int t = threadIdx.x;
    const int w = t >> 6;          // h-eighth
    const int l = t & 63;
    const int row0 = blockIdx.x * 128;
    const int h0 = w * 128;

    const float* x0 = seq + (size_t)(row0 + l) * HH + h0;        // row A
    const float* x1 = seq + (size_t)(row0 + l + 64) * HH + h0;   // row B
    const float* wb = W + (size_t)h0 * CC;                        // uniform

    float acc0[CC], acc1[CC];
#pragma unroll
    for (int c = 0; c < CC; ++c) { acc0[c] = 0.f; acc1[c] = 0.f; }

    float4 xa[4], xbv[4], xan[4], xbn[4];
    float wr[6], wrn[6];

    // chunk 0 loads
#pragma unroll
    for (int k = 0; k < 4; ++k) {
        xa[k]  = *(const float4*)(x0 + k * 4);
        xbv[k] = *(const float4*)(x1 + k * 4);
    }
#pragma unroll
    for (int i = 0; i < 6; ++i) {
        int j = i * 64 + l;
        wr[i] = (j < 16 * CC) ? wb[j] : 0.f;
    }

#pragma unroll 2
    for (int ch = 0; ch < 8; ++ch) {
        if (ch < 7) {   // depth-1 prefetch of chunk ch+1
            const float* px0 = x0 + (ch + 1) * 16;
            const float* px1 = x1 + (ch + 1) * 16;
#pragma unroll
            for (int k = 0; k < 4; ++k) {
                xan[k] = *(const float4*)(px0 + k * 4);
                xbn[k] = *(const float4*)(px1 + k * 4);
            }
            const float* pw = wb + (ch + 1) * 16 * CC;
#pragma unroll
            for (int i = 0; i < 6; ++i) {
                int j = i * 64 + l;
                wrn[i] = (j < 16 * CC) ? pw[j] : 0.f;
            }
        }

        // compute: 16 h x 21 c, W broadcast via readlane (static indices)
#pragma unroll
        for (int g = 0; g < 4; ++g) {
#pragma unroll
            for (int j = 0; j < 4; ++j) {
                float xv0 = (&xa[g].x)[j];
                float xv1 = (&xbv[g].x)[j];
#pragma unroll
                for (int c = 0; c < CC; ++c) {
                    const int idx = (g * 4 + j) * CC + c;   // 0..335, static
                    float s = RL(wr[idx >> 6], idx & 63);
                    acc0[c] = fmaf(s, xv0, acc0[c]);
                    acc1[c] = fmaf(s, xv1, acc1[c]);
                }
            }
        }

        if (ch < 7) {   // rotate buffers (renamed away under unroll-2)
#pragma unroll
            for (int k = 0; k < 4; ++k) { xa[k] = xan[k]; xbv[k] = xbn[k]; }
#pragma unroll
            for (int i = 0; i < 6; ++i) wr[i] = wrn[i];
        }
    }

    // 8-way combine: waves 1..7 dump partials, wave 0 sums + bias + store
    if (w > 0) {
#pragma unroll
        for (int c = 0; c < CC; ++c) {
            comb[w - 1][l][c]      = acc0[c];
            comb[w - 1][l + 64][c] = acc1[c];
        }
    }
    __syncthreads();
    if (w == 0) {
        float* o0 = logits + (size_t)(row0 + l) * CC;
        float* o1 = logits + (size_t)(row0 + l + 64) * CC;
#pragma unroll
        for (int c = 0; c < CC; ++c) {
            float s0 = acc0[c] + bias[c];
            float s1 = acc1[c] + bias[c];
#pragma unroll
            for (int i = 0; i < 7; ++i) {
                s0 += comb[i][l][c];
                s1 += comb[i][l + 64][c];
            }
            o0[c] = s0;
            o1[c] = s1;
        }
    }
}

// ---------------------------------------------------------------------------
// K2: Viterbi — round-5 structure verbatim (round-6's scan rewrite regressed
// 49->86us; reverted). Wave 0: serial forward scan (21 readlane+add, max3
// tree, add), state history to LDS. Backpointers recomputed in parallel
// (bit-exact). Backtrack via 12 chunked candidate pointer-maps. One-hot by
// 252 threads.
// ---------------------------------------------------------------------------
__global__ __launch_bounds__(256) void viterbi_kernel(
    const float* __restrict__ logits,  // [B, T, C]
    const int* __restrict__ mask,      // [B, T]
    const float* __restrict__ trans,   // [C, C]
    float* __restrict__ onehot)        // [B, T, C]
{
    __shared__ __align__(16) float lg[(TT + 1) * CC];   // +1 row: prefetch pad
    __shared__ float stS[TT * CC];
    __shared__ float trL[CC * CC];
    __shared__ unsigned char bp[TT * CC];
    __shared__ unsigned char tagl[TT];
    __shared__ unsigned char mapl[12 * CC];
    __shared__ unsigned char bnd[13];

    const int tid = threadIdx.x;
    const int w = tid >> 6;
    const int l = tid & 63;
    const int b = blockIdx.x;

    // stage logits[b] -> LDS
    const float* lb = logits + (size_t)b * TT * CC;
    for (int i = w; i < 42; i += 4)
        gll16(lb + (size_t)(i * 64 + l) * 4, &lg[i * 256]);

    for (int j = tid; j < CC * CC; j += 256) trL[j] = trans[j];

    int sl = 0;
#pragma unroll
    for (int k = 0; k < 8; ++k) sl += mask[b * TT + k * 64 + l];
#pragma unroll
    for (int o = 32; o > 0; o >>= 1) sl += __shfl_xor(sl, o);
    const int idstart = (sl >= 1) ? (sl - 1) : 0;

    asm volatile("s_waitcnt vmcnt(0)" ::: "memory");
    __syncthreads();

    if (w == 0) {
        // ---- forward scan ----
        const bool act = (l < CC);
        const int cc = act ? l : 0;
        float tcol[CC];
#pragma unroll
        for (int cp = 0; cp < CC; ++cp) tcol[cp] = trL[cp * CC + cc];

        float st = lg[cc];
        if (act) stS[l] = st;
        float lgt_next = lg[CC + cc];

#pragma unroll 1
        for (int t = 1; t < sl; ++t) {
            float lgt = lgt_next;
            lgt_next = lg[(t + 1) * CC + cc];
            float sc[CC];
#pragma unroll
            for (int cp = 0; cp < CC; ++cp) sc[cp] = RL(st, cp) + tcol[cp];
            float m0 = fmaxf(fmaxf(sc[0], sc[1]), sc[2]);
            float m1 = fmaxf(fmaxf(sc[3], sc[4]), sc[5]);
            float m2 = fmaxf(fmaxf(sc[6], sc[7]), sc[8]);
            float m3 = fmaxf(fmaxf(sc[9], sc[10]), sc[11]);
            float m4 = fmaxf(fmaxf(sc[12], sc[13]), sc[14]);
            float m5 = fmaxf(fmaxf(sc[15], sc[16]), sc[17]);
            float m6 = fmaxf(fmaxf(sc[18], sc[19]), sc[20]);
            float n0 = fmaxf(fmaxf(m0, m1), m2);
            float n1 = fmaxf(fmaxf(m3, m4), m5);
            float best = fmaxf(fmaxf(n0, n1), m6);
            st = best + lgt;
            if (act) stS[t * CC + l] = st;
        }

        // last_tag = first-max over final state
        float fs[CC];
#pragma unroll
        for (int cp = 0; cp < CC; ++cp) fs[cp] = RL(st, cp);
        float q0 = fmaxf(fmaxf(fs[0], fs[1]), fs[2]);
        float q1 = fmaxf(fmaxf(fs[3], fs[4]), fs[5]);
        float q2 = fmaxf(fmaxf(fs[6], fs[7]), fs[8]);
        float q3 = fmaxf(fmaxf(fs[9], fs[10]), fs[11]);
        float q4 = fmaxf(fmaxf(fs[12], fs[13]), fs[14]);
        float q5 = fmaxf(fmaxf(fs[15], fs[16]), fs[17]);
        float q6 = fmaxf(fmaxf(fs[18], fs[19]), fs[20]);
        float fbest = fmaxf(fmaxf(fmaxf(q0, q1), fmaxf(q2, q3)),
                            fmaxf(fmaxf(q4, q5), q6));
        int e[CC];
#pragma unroll
        for (int cp = 0; cp < CC; ++cp) e[cp] = (fs[cp] == fbest) ? cp : 63;
        int i0 = min(min(e[0], e[1]), e[2]);
        int i1 = min(min(e[3], e[4]), e[5]);
        int i2 = min(min(e[6], e[7]), e[8]);
        int i3 = min(min(e[9], e[10]), e[11]);
        int i4 = min(min(e[12], e[13]), e[14]);
        int i5 = min(min(e[15], e[16]), e[17]);
        int i6 = min(min(e[18], e[19]), e[20]);
        int last = min(min(min(i0, i1), min(i2, i3)), min(min(i4, i5), i6));
        if (l == 0) tagl[TT - 1] = (unsigned char)last;
    } else {
        // identity backpointers for p in [idstart, TT)
        int s = (w - 1) * 64 + l;                  // 0..191
        if (s < 189) {
            int c0 = s % CC, prow = s / CC;        // 9 rows/pass
#pragma unroll 1
            for (int p = idstart + prow; p < TT; p += 9)
                bp[p * CC + c0] = (unsigned char)c0;
        }
    }
    __syncthreads();

    // ---- parallel bp recompute for valid steps ----
    if (tid < 252) {
        const int c0 = tid % CC, tg = tid / CC;    // 12 rows/pass
        float tc[CC];
#pragma unroll
        for (int cp = 0; cp < CC; ++cp) tc[cp] = trL[cp * CC + c0];
#pragma unroll 1
        for (int t = 1 + tg; t < sl; t += 12) {
            const float* sp = stS + (t - 1) * CC;
            float bv = sp[0] + tc[0];
            int bi = 0;
#pragma unroll
            for (int cp = 1; cp < CC; ++cp) {
                float v = sp[cp] + tc[cp];
                bool g = v > bv;                   // strict >: first-max
                bv = g ? v : bv;
                bi = g ? cp : bi;
            }
            bp[(t - 1) * CC + c0] = (unsigned char)bi;
        }
    }
    __syncthreads();

    // ---- Phase A: candidate maps for 12 chunks of 43 steps ----
    if (tid < 252) {
        int g = tid / CC, cand = tid % CC;
        int endp = g * 43;
        int startp = min(g * 43 + 42, TT - 2);
        int m = cand;
#pragma unroll 1
        for (int i = 0; i < 43; ++i) {
            int p = startp - i;
            int pr = (p >= endp) ? p : endp;
            int m2 = bp[pr * CC + m];
            m = (p >= endp) ? m2 : m;
        }
        mapl[g * CC + cand] = (unsigned char)m;
    }
    __syncthreads();

    // ---- Phase B: compose boundary tags ----
    if (tid == 0) {
        int eb = tagl[TT - 1];
        bnd[12] = (unsigned char)eb;
        for (int g = 11; g >= 0; --g) {
            eb = mapl[g * CC + eb];
            bnd[g] = (unsigned char)eb;
        }
    }
    __syncthreads();

    // ---- Phase C: replay 12 chunks in parallel ----
    if (tid < 12) {
        int g = tid;
        int endp = g * 43;
        int startp = min(g * 43 + 42, TT - 2);
        int eb = bnd[g + 1];
#pragma unroll 1
        for (int p = startp; p >= endp; --p) {
            eb = bp[p * CC + eb];
            tagl[p] = (unsigned char)eb;
        }
    }
    __syncthreads();

    // ---- Phase D: one-hot write ----
    if (tid < 252) {
        const int c0 = tid % CC, prow = tid / CC;
        float* ob = onehot + (size_t)b * TT * CC;
#pragma unroll 1
        for (int p = prow; p < TT; p += 12)
            ob[(size_t)p * CC + c0] = (c0 == (int)tagl[p]) ? 1.f : 0.f;
    }
}

extern "C" void kernel_launch(void* const* d_in, const int* in_sizes, int n_in,
                              void* d_out, int out_size, void* d_ws, size_t ws_size,
                              hipStream_t stream) {
    const float* seq   = (const float*)d_in[0];  // [B,T,H] f32
    const int*   msk   = (const int*)d_in[1];    // [B,T] i32
    const float* W     = (const float*)d_in[2];  // [H,C] f32
    const float* bias  = (const float*)d_in[3];  // [C] f32
    const float* trans = (const float*)d_in[4];  // [C,C] f32

    float* onehot_out = (float*)d_out;                     // output 0: [B,T,C]
    float* logits_out = onehot_out + (size_t)BB * TT * CC; // output 1: [B,T,C]

    logits_kernel<<<256, 512, 0, stream>>>(seq, W, bias, logits_out);
    viterbi_kernel<<<BB, 256, 0, stream>>>(logits_out, msk, trans, onehot_out);
}